// Round 1
// baseline (4361.650 us; speedup 1.0000x reference)
//
#include <hip/hip_runtime.h>

// QuantumQLSTM on MI355X.
// Decomposition: zx[t,b,16] = x @ Wx^T + b precomputed (parallel, memory-bound);
// recurrent kernel: 64 persistent blocks, 4 batch rows each, state (hx,cx) in LDS.
// Per step, only the [256 rows x 4] gate vector crosses blocks, via a
// double-buffered global buffer + monotonic per-block flags (device-scope
// atomics; per-XCD L2 non-coherence handled by release store / __threadfence).

#define T_DIM 512
#define B_DIM 256
#define D_DIM 256
#define H_DIM 256
#define DH    512   // D + H
#define NG    16    // 4 gates * NQ(4)
#define NB    64    // persistent blocks (<= 256 CUs -> all co-resident)
#define ROWS  4     // batch rows per block (NB*ROWS == B_DIM)
#define PAD   260   // LDS row stride in floats (16B-aligned, bank-spread)

// -------------------- zx precompute: zx[(t*B+b)*16+q] = b_q + x[t,b,:] . Wx[q,:]
__global__ __launch_bounds__(256) void zx_kernel(
    const float* __restrict__ x,
    const float* __restrict__ Wf, const float* __restrict__ Wi,
    const float* __restrict__ Wu, const float* __restrict__ Wo,
    const float* __restrict__ bf, const float* __restrict__ bi,
    const float* __restrict__ bu, const float* __restrict__ bo,
    float* __restrict__ zx)
{
    __shared__ float Wl[NG][PAD];
    __shared__ float Xl[16][PAD];
    const int tid = threadIdx.x;

    // W x-part (cols 0..255 of the stride-512 rows), 16 rows
    for (int e = tid; e < NG * 64; e += 256) {
        int q16 = e >> 6, c4 = (e & 63) * 4;
        int g = q16 >> 2, qj = q16 & 3;
        const float* W = (g == 0) ? Wf : (g == 1) ? Wi : (g == 2) ? Wu : Wo;
        *(float4*)&Wl[q16][c4] = *(const float4*)(W + qj * DH + c4);
    }
    // 16 consecutive (t,b) rows of x -> LDS
    const long base = (long)blockIdx.x * 16 * D_DIM;
    for (int e = tid; e < 16 * 64; e += 256) {
        int r = e >> 6, c4 = (e & 63) * 4;
        *(float4*)&Xl[r][c4] = *(const float4*)(x + base + r * D_DIM + c4);
    }
    __syncthreads();

    const int q16 = tid & 15, r = tid >> 4;   // tid == r*16+q16 -> coalesced store
    const int g = q16 >> 2, qj = q16 & 3;
    const float* bv = (g == 0) ? bf : (g == 1) ? bi : (g == 2) ? bu : bo;
    float acc = bv[qj];
    #pragma unroll 4
    for (int k = 0; k < D_DIM; k += 4) {
        float4 xv = *(float4*)&Xl[r][k];
        float4 wv = *(float4*)&Wl[q16][k];
        acc += xv.x * wv.x + xv.y * wv.y + xv.z * wv.z + xv.w * wv.w;
    }
    zx[(long)blockIdx.x * 256 + tid] = acc;
}

// -------------------- recurrent kernel
__global__ __launch_bounds__(256) void rec_kernel(
    const float* __restrict__ Wf, const float* __restrict__ Wi,
    const float* __restrict__ Wu, const float* __restrict__ Wo,
    const float* __restrict__ phf, const float* __restrict__ phi,
    const float* __restrict__ phu, const float* __restrict__ pho,
    const float* __restrict__ zx,
    float* __restrict__ out,          // [T*B*H] outs, then [B*H] hx, then [B*H] cx
    float* __restrict__ gbuf,         // [2][B_DIM][4] (f,i,g,o per hidden index)
    unsigned int* __restrict__ flags) // [2][NB], zeroed before launch
{
    __shared__ float Wl[NG][PAD];     // W h-part
    __shared__ float hxl[ROWS][PAD];
    __shared__ float cxl[ROWS][PAD];
    const int tid = threadIdx.x;
    const int blk = blockIdx.x;

    for (int e = tid; e < NG * 64; e += 256) {
        int q16 = e >> 6, c4 = (e & 63) * 4;
        int g = q16 >> 2, qj = q16 & 3;
        const float* W = (g == 0) ? Wf : (g == 1) ? Wi : (g == 2) ? Wu : Wo;
        *(float4*)&Wl[q16][c4] = *(const float4*)(W + qj * DH + 256 + c4);
    }
    for (int e = tid; e < ROWS * PAD; e += 256) {
        ((float*)hxl)[e] = 0.0f;
        ((float*)cxl)[e] = 0.0f;
    }

    // phase-1 identity: tid = r1(2b) | ks(2b) | q(4b); wave w == gate w
    const int r1   = tid & 3;
    const int ks   = (tid >> 2) & 3;
    const int q    = tid >> 4;            // 0..15 = gate*4 + j
    const int gate = q >> 2, j = q & 3;
    const int row_g = blk * ROWS + r1;
    const float* phiP = (gate == 0) ? phf : (gate == 1) ? phi : (gate == 2) ? phu : pho;
    const float phi_q = phiP[j];
    // phase-2 identity: one wave per row, lanes sweep hidden columns
    const int r2   = tid >> 6;
    const int lane = tid & 63;
    const int row_g2 = blk * ROWS + r2;

    __syncthreads();

    float zx_next = zx[((long)0 * B_DIM + row_g) * NG + q];  // prefetch t=0

    for (int t = 0; t < T_DIM; ++t) {
        const int slot = t & 1;

        // ---- phase 1: z = zx + hx . Wh  (thread: row r1, output q, k-range 64)
        float acc = 0.0f;
        #pragma unroll
        for (int i = 0; i < 16; ++i) {
            float4 h4 = *(float4*)&hxl[r1][ks * 64 + i * 4];
            float4 w4 = *(float4*)&Wl[q][ks * 64 + i * 4];
            acc += h4.x * w4.x + h4.y * w4.y + h4.z * w4.z + h4.w * w4.w;
        }
        acc += __shfl_xor(acc, 4);   // reduce ks (bits 2,3)
        acc += __shfl_xor(acc, 8);
        const float z = zx_next + acc;
        // qgate: product of cos over j=1,2,3 (j=0 contributes 1)
        float c = (j == 0) ? 1.0f : cosf(z + phi_q);
        float p = c * __shfl_xor(c, 16);   // butterfly over j (bits 4,5)
        p = p * __shfl_xor(p, 32);
        const float gv = (gate == 2) ? tanhf(p) : 1.0f / (1.0f + __expf(-p));

        if ((tid & 60) == 0) {   // ks==0 && j==0 : one publisher per (row, gate)
            gbuf[((long)slot * B_DIM + row_g) * 4 + gate] = gv;
        }
        __syncthreads();   // drains vmcnt: gate stores of all 4 waves complete
        if (tid == 0) {
            __hip_atomic_store(&flags[slot * NB + blk], (unsigned)(t + 1),
                               __ATOMIC_RELEASE, __HIP_MEMORY_SCOPE_AGENT);
        }
        // ---- spin: one wave, one flag per lane (NB == 64)
        if (tid < NB) {
            while (__hip_atomic_load(&flags[slot * NB + tid],
                                     __ATOMIC_RELAXED, __HIP_MEMORY_SCOPE_AGENT)
                   < (unsigned)(t + 1)) { /* spin */ }
        }
        __syncthreads();
        __threadfence();   // acquire: invalidate caches before reading gbuf

        // ---- phase 2: read full gate vector, update owned rows
        const float4* gb = (const float4*)(gbuf + (long)slot * B_DIM * 4);
        float4 gv4[4];
        #pragma unroll
        for (int m = 0; m < 4; ++m) gv4[m] = gb[lane + m * 64];

        const int tn = (t + 1 < T_DIM) ? (t + 1) : t;   // prefetch next zx
        zx_next = zx[((long)tn * B_DIM + row_g) * NG + q];

        #pragma unroll
        for (int m = 0; m < 4; ++m) {
            const int col = lane + m * 64;
            const float4 g4 = gv4[m];           // x=f, y=i, z=g(update), w=o
            const float cold = cxl[r2][col];
            const float cnew = g4.x * cold + g4.y * g4.z;
            const float th = tanhf(cnew);
            const float h = g4.w * th;
            cxl[r2][col] = cnew;
            hxl[r2][col] = h;
            out[(long)t * (B_DIM * H_DIM) + (long)row_g2 * H_DIM + col] = h;
        }
        __syncthreads();   // hxl/cxl visible before next phase 1
    }

    // final hx, cx tails
    const long base_h = (long)T_DIM * B_DIM * H_DIM;
    #pragma unroll
    for (int m = 0; m < 4; ++m) {
        const int col = lane + m * 64;
        out[base_h + (long)row_g2 * H_DIM + col] = hxl[r2][col];
        out[base_h + (long)B_DIM * H_DIM + (long)row_g2 * H_DIM + col] = cxl[r2][col];
    }
}

extern "C" void kernel_launch(void* const* d_in, const int* in_sizes, int n_in,
                              void* d_out, int out_size, void* d_ws, size_t ws_size,
                              hipStream_t stream) {
    (void)in_sizes; (void)n_in; (void)out_size; (void)ws_size;
    const float* x   = (const float*)d_in[0];
    const float* Wf  = (const float*)d_in[1];
    const float* bf  = (const float*)d_in[2];
    const float* phf = (const float*)d_in[3];
    const float* Wi  = (const float*)d_in[4];
    const float* bi  = (const float*)d_in[5];
    const float* phi = (const float*)d_in[6];
    const float* Wu  = (const float*)d_in[7];
    const float* bu  = (const float*)d_in[8];
    const float* phu = (const float*)d_in[9];
    const float* Wo  = (const float*)d_in[10];
    const float* bo  = (const float*)d_in[11];
    const float* pho = (const float*)d_in[12];

    float* zx   = (float*)d_ws;                              // T*B*16 floats = 8.39 MB
    float* gbuf = zx + (size_t)T_DIM * B_DIM * NG;           // 2*256*4 floats
    unsigned int* flags = (unsigned int*)(gbuf + 2 * B_DIM * 4);  // 2*NB u32

    // flags MUST be zeroed every call (d_ws is poisoned to 0xAA between calls,
    // which would otherwise satisfy every spin instantly).
    hipMemsetAsync(flags, 0, 2 * NB * sizeof(unsigned int), stream);

    zx_kernel<<<(T_DIM * B_DIM) / 16, 256, 0, stream>>>(
        x, Wf, Wi, Wu, Wo, bf, bi, bu, bo, zx);

    rec_kernel<<<NB, 256, 0, stream>>>(
        Wf, Wi, Wu, Wo, phf, phi, phu, pho, zx,
        (float*)d_out, gbuf, flags);
}

// Round 2
// 2250.988 us; speedup vs baseline: 1.9377x; 1.9377x over previous
//
#include <hip/hip_runtime.h>

// QuantumQLSTM on MI355X.
// zx[t,b,16] = x @ Wx^T + b precomputed (parallel, memory-bound);
// recurrent kernel: 64 persistent blocks, 4 batch rows each, state (hx,cx) in LDS.
// Per step, only the [256 rows x 4] gate vector crosses blocks.
//
// R1 lesson: release-store (+__threadfence) at agent scope emit L2
// writeback/invalidate every step -> 20k cyc/step stall (VALUBusy 1%).
// R2: ALL cross-block traffic uses RELAXED agent-scope atomics (sc1 ops that
// bypass L1/L2 straight to the coherent LLC). Ordering of gbuf-stores vs the
// flag-store comes from __syncthreads (each wave drains vmcnt at the barrier,
// so every gate value has reached the LLC before tid0 stores the flag).
// No release/acquire fences anywhere in the step loop.

#define T_DIM 512
#define B_DIM 256
#define D_DIM 256
#define H_DIM 256
#define DH    512   // D + H
#define NG    16    // 4 gates * NQ(4)
#define NB    64    // persistent blocks (<= 256 CUs -> all co-resident)
#define ROWS  4     // batch rows per block (NB*ROWS == B_DIM)
#define PAD   260   // LDS row stride in floats (16B-aligned, bank-spread)

// -------------------- zx precompute: zx[(t*B+b)*16+q] = b_q + x[t,b,:] . Wx[q,:]
__global__ __launch_bounds__(256) void zx_kernel(
    const float* __restrict__ x,
    const float* __restrict__ Wf, const float* __restrict__ Wi,
    const float* __restrict__ Wu, const float* __restrict__ Wo,
    const float* __restrict__ bf, const float* __restrict__ bi,
    const float* __restrict__ bu, const float* __restrict__ bo,
    float* __restrict__ zx)
{
    __shared__ float Wl[NG][PAD];
    __shared__ float Xl[16][PAD];
    const int tid = threadIdx.x;

    for (int e = tid; e < NG * 64; e += 256) {
        int q16 = e >> 6, c4 = (e & 63) * 4;
        int g = q16 >> 2, qj = q16 & 3;
        const float* W = (g == 0) ? Wf : (g == 1) ? Wi : (g == 2) ? Wu : Wo;
        *(float4*)&Wl[q16][c4] = *(const float4*)(W + qj * DH + c4);
    }
    const long base = (long)blockIdx.x * 16 * D_DIM;
    for (int e = tid; e < 16 * 64; e += 256) {
        int r = e >> 6, c4 = (e & 63) * 4;
        *(float4*)&Xl[r][c4] = *(const float4*)(x + base + r * D_DIM + c4);
    }
    __syncthreads();

    const int q16 = tid & 15, r = tid >> 4;   // tid == r*16+q16 -> coalesced store
    const int g = q16 >> 2, qj = q16 & 3;
    const float* bv = (g == 0) ? bf : (g == 1) ? bi : (g == 2) ? bu : bo;
    float acc = bv[qj];
    #pragma unroll 4
    for (int k = 0; k < D_DIM; k += 4) {
        float4 xv = *(float4*)&Xl[r][k];
        float4 wv = *(float4*)&Wl[q16][k];
        acc += xv.x * wv.x + xv.y * wv.y + xv.z * wv.z + xv.w * wv.w;
    }
    zx[(long)blockIdx.x * 256 + tid] = acc;
}

// -------------------- recurrent kernel
__global__ __launch_bounds__(256) void rec_kernel(
    const float* __restrict__ Wf, const float* __restrict__ Wi,
    const float* __restrict__ Wu, const float* __restrict__ Wo,
    const float* __restrict__ phf, const float* __restrict__ phi,
    const float* __restrict__ phu, const float* __restrict__ pho,
    const float* __restrict__ zx,
    float* __restrict__ out,          // [T*B*H] outs, then [B*H] hx, then [B*H] cx
    unsigned int* __restrict__ gbuf,  // [2][B_DIM][4] float bits (f,i,g,o)
    unsigned int* __restrict__ flags) // [2][NB], zeroed before launch
{
    __shared__ float Wl[NG][PAD];     // W h-part
    __shared__ float hxl[ROWS][PAD];
    __shared__ float cxl[ROWS][PAD];
    const int tid = threadIdx.x;
    const int blk = blockIdx.x;

    for (int e = tid; e < NG * 64; e += 256) {
        int q16 = e >> 6, c4 = (e & 63) * 4;
        int g = q16 >> 2, qj = q16 & 3;
        const float* W = (g == 0) ? Wf : (g == 1) ? Wi : (g == 2) ? Wu : Wo;
        *(float4*)&Wl[q16][c4] = *(const float4*)(W + qj * DH + 256 + c4);
    }
    for (int e = tid; e < ROWS * PAD; e += 256) {
        ((float*)hxl)[e] = 0.0f;
        ((float*)cxl)[e] = 0.0f;
    }

    // phase-1 identity: tid = r1(2b) | ks(2b) | q(4b); wave w == gate w
    const int r1   = tid & 3;
    const int ks   = (tid >> 2) & 3;
    const int q    = tid >> 4;            // 0..15 = gate*4 + j
    const int gate = q >> 2, j = q & 3;
    const int row_g = blk * ROWS + r1;
    const float* phiP = (gate == 0) ? phf : (gate == 1) ? phi : (gate == 2) ? phu : pho;
    const float phi_q = phiP[j];
    // phase-2 identity: one wave per row, lanes sweep hidden columns
    const int r2   = tid >> 6;
    const int lane = tid & 63;
    const int row_g2 = blk * ROWS + r2;

    __syncthreads();

    float zx_next = zx[((long)0 * B_DIM + row_g) * NG + q];  // prefetch t=0

    for (int t = 0; t < T_DIM; ++t) {
        const int slot = t & 1;

        // ---- phase 1: z = zx + hx . Wh  (thread: row r1, output q, k-range 64)
        float acc = 0.0f;
        #pragma unroll
        for (int i = 0; i < 16; ++i) {
            float4 h4 = *(float4*)&hxl[r1][ks * 64 + i * 4];
            float4 w4 = *(float4*)&Wl[q][ks * 64 + i * 4];
            acc += h4.x * w4.x + h4.y * w4.y + h4.z * w4.z + h4.w * w4.w;
        }
        acc += __shfl_xor(acc, 4);   // reduce ks (bits 2,3)
        acc += __shfl_xor(acc, 8);
        const float z = zx_next + acc;
        // qgate: product of cos over j=1,2,3 (j=0 contributes 1)
        float c = (j == 0) ? 1.0f : cosf(z + phi_q);
        float p = c * __shfl_xor(c, 16);   // butterfly over j (bits 4,5)
        p = p * __shfl_xor(p, 32);
        const float gv = (gate == 2) ? tanhf(p) : 1.0f / (1.0f + __expf(-p));

        if ((tid & 60) == 0) {   // ks==0 && j==0 : one publisher per (row, gate)
            __hip_atomic_store(&gbuf[((long)slot * B_DIM + row_g) * 4 + gate],
                               __float_as_uint(gv),
                               __ATOMIC_RELAXED, __HIP_MEMORY_SCOPE_AGENT);
        }
        // barrier drains each wave's vmcnt -> all 16 gate values are at the LLC
        __syncthreads();
        if (tid == 0) {
            __hip_atomic_store(&flags[slot * NB + blk], (unsigned)(t + 1),
                               __ATOMIC_RELAXED, __HIP_MEMORY_SCOPE_AGENT);
        }
        // ---- spin: one wave, one flag per lane (NB == 64)
        if (tid < NB) {
            while (__hip_atomic_load(&flags[slot * NB + tid],
                                     __ATOMIC_RELAXED, __HIP_MEMORY_SCOPE_AGENT)
                   < (unsigned)(t + 1)) { /* spin */ }
        }
        __syncthreads();   // NO fence: gbuf reads below are LLC-direct atomics

        // ---- phase 2: read full gate vector (b64 LLC loads), update owned rows
        const unsigned long long* gb64 =
            (const unsigned long long*)(gbuf + (long)slot * B_DIM * 4);
        float4 gv4[4];
        #pragma unroll
        for (int m = 0; m < 4; ++m) {
            const int col = lane + m * 64;
            unsigned long long lo = __hip_atomic_load(&gb64[col * 2 + 0],
                __ATOMIC_RELAXED, __HIP_MEMORY_SCOPE_AGENT);
            unsigned long long hi = __hip_atomic_load(&gb64[col * 2 + 1],
                __ATOMIC_RELAXED, __HIP_MEMORY_SCOPE_AGENT);
            gv4[m].x = __uint_as_float((unsigned)(lo & 0xffffffffu));
            gv4[m].y = __uint_as_float((unsigned)(lo >> 32));
            gv4[m].z = __uint_as_float((unsigned)(hi & 0xffffffffu));
            gv4[m].w = __uint_as_float((unsigned)(hi >> 32));
        }

        const int tn = (t + 1 < T_DIM) ? (t + 1) : t;   // prefetch next zx
        zx_next = zx[((long)tn * B_DIM + row_g) * NG + q];

        #pragma unroll
        for (int m = 0; m < 4; ++m) {
            const int col = lane + m * 64;
            const float4 g4 = gv4[m];           // x=f, y=i, z=g(update), w=o
            const float cold = cxl[r2][col];
            const float cnew = g4.x * cold + g4.y * g4.z;
            const float th = tanhf(cnew);
            const float h = g4.w * th;
            cxl[r2][col] = cnew;
            hxl[r2][col] = h;
            out[(long)t * (B_DIM * H_DIM) + (long)row_g2 * H_DIM + col] = h;
        }
        __syncthreads();   // hxl/cxl visible before next phase 1
    }

    // final hx, cx tails
    const long base_h = (long)T_DIM * B_DIM * H_DIM;
    #pragma unroll
    for (int m = 0; m < 4; ++m) {
        const int col = lane + m * 64;
        out[base_h + (long)row_g2 * H_DIM + col] = hxl[r2][col];
        out[base_h + (long)B_DIM * H_DIM + (long)row_g2 * H_DIM + col] = cxl[r2][col];
    }
}

extern "C" void kernel_launch(void* const* d_in, const int* in_sizes, int n_in,
                              void* d_out, int out_size, void* d_ws, size_t ws_size,
                              hipStream_t stream) {
    (void)in_sizes; (void)n_in; (void)out_size; (void)ws_size;
    const float* x   = (const float*)d_in[0];
    const float* Wf  = (const float*)d_in[1];
    const float* bf  = (const float*)d_in[2];
    const float* phf = (const float*)d_in[3];
    const float* Wi  = (const float*)d_in[4];
    const float* bi  = (const float*)d_in[5];
    const float* phi = (const float*)d_in[6];
    const float* Wu  = (const float*)d_in[7];
    const float* bu  = (const float*)d_in[8];
    const float* phu = (const float*)d_in[9];
    const float* Wo  = (const float*)d_in[10];
    const float* bo  = (const float*)d_in[11];
    const float* pho = (const float*)d_in[12];

    float* zx = (float*)d_ws;                                  // T*B*16 floats = 8.39 MB
    unsigned int* gbuf = (unsigned int*)(zx + (size_t)T_DIM * B_DIM * NG); // 2*256*4 u32
    unsigned int* flags = gbuf + 2 * B_DIM * 4;                // 2*NB u32

    // flags MUST be zeroed every call (d_ws is poisoned to 0xAA between calls,
    // which would otherwise satisfy every spin instantly).
    hipMemsetAsync(flags, 0, 2 * NB * sizeof(unsigned int), stream);

    zx_kernel<<<(T_DIM * B_DIM) / 16, 256, 0, stream>>>(
        x, Wf, Wi, Wu, Wo, bf, bi, bu, bo, zx);

    rec_kernel<<<NB, 256, 0, stream>>>(
        Wf, Wi, Wu, Wo, phf, phi, phu, pho, zx,
        (float*)d_out, gbuf, flags);
}

// Round 3
// 1761.296 us; speedup vs baseline: 2.4764x; 1.2780x over previous
//
#include <hip/hip_runtime.h>

// QuantumQLSTM on MI355X.
// zx[t,b,16] = x @ Wx^T + b precomputed (parallel); recurrent kernel: 64
// persistent blocks, 4 batch rows each, state (hx,cx) in LDS.
//
// R1: release/acquire fences at agent scope -> L2 writeback/inv each step (4250us).
// R2: relaxed LLC atomics + flag indirection -> 9.4k cyc/step, 98% stall (2010us).
// R3: single-word sync. Each gate value is published as ONE b64 relaxed agent
// atomic packing (tag = t+1 in hi32, f32 value in lo32). Tag+data atomicity in
// one word removes ALL ordering needs: no pre-flag barrier, no flag store, no
// dependent data read. Readers poll the 4 words of their own column directly.
// One __syncthreads per step (hx/cx LDS hazard). Poison tag 0xAAAAAAAA never
// matches a wanted tag (1..512) -> no memset needed; 2-slot parity reuse is
// safe because publishing step t+3 requires having read everyone's t+2, which
// requires everyone finished reading t+1.

#define T_DIM 512
#define B_DIM 256
#define D_DIM 256
#define H_DIM 256
#define DH    512   // D + H
#define NG    16    // 4 gates * NQ(4)
#define NB    64    // persistent blocks
#define ROWS  4     // batch rows per block
#define PAD   260   // zx_kernel LDS row stride (unchanged, known-good)
#define CH    68    // rec LDS chunk stride: 64 floats + 4 pad (bank spread)
#define RPAD  272   // rec LDS row stride = 4*CH; 272%32==16 -> uniform 2-way banks

__device__ __forceinline__ float fast_sigmoid(float x) {
    return 1.0f / (1.0f + __expf(-x));
}
__device__ __forceinline__ float fast_tanh(float x) {
    // inputs bounded: |x| <= ~2.1 (cx contraction: f <= sigmoid(1) = 0.731)
    float e = __expf(2.0f * x);
    return (e - 1.0f) / (e + 1.0f);
}

// -------------------- zx precompute: zx[(t*B+b)*16+q] = b_q + x[t,b,:] . Wx[q,:]
__global__ __launch_bounds__(256) void zx_kernel(
    const float* __restrict__ x,
    const float* __restrict__ Wf, const float* __restrict__ Wi,
    const float* __restrict__ Wu, const float* __restrict__ Wo,
    const float* __restrict__ bf, const float* __restrict__ bi,
    const float* __restrict__ bu, const float* __restrict__ bo,
    float* __restrict__ zx)
{
    __shared__ float Wl[NG][PAD];
    __shared__ float Xl[16][PAD];
    const int tid = threadIdx.x;

    for (int e = tid; e < NG * 64; e += 256) {
        int q16 = e >> 6, c4 = (e & 63) * 4;
        int g = q16 >> 2, qj = q16 & 3;
        const float* W = (g == 0) ? Wf : (g == 1) ? Wi : (g == 2) ? Wu : Wo;
        *(float4*)&Wl[q16][c4] = *(const float4*)(W + qj * DH + c4);
    }
    const long base = (long)blockIdx.x * 16 * D_DIM;
    for (int e = tid; e < 16 * 64; e += 256) {
        int r = e >> 6, c4 = (e & 63) * 4;
        *(float4*)&Xl[r][c4] = *(const float4*)(x + base + r * D_DIM + c4);
    }
    __syncthreads();

    const int q16 = tid & 15, r = tid >> 4;
    const int g = q16 >> 2, qj = q16 & 3;
    const float* bv = (g == 0) ? bf : (g == 1) ? bi : (g == 2) ? bu : bo;
    float acc = bv[qj];
    #pragma unroll 4
    for (int k = 0; k < D_DIM; k += 4) {
        float4 xv = *(float4*)&Xl[r][k];
        float4 wv = *(float4*)&Wl[q16][k];
        acc += xv.x * wv.x + xv.y * wv.y + xv.z * wv.z + xv.w * wv.w;
    }
    zx[(long)blockIdx.x * 256 + tid] = acc;
}

// -------------------- recurrent kernel
__global__ __launch_bounds__(256) void rec_kernel(
    const float* __restrict__ Wf, const float* __restrict__ Wi,
    const float* __restrict__ Wu, const float* __restrict__ Wo,
    const float* __restrict__ phf, const float* __restrict__ phi,
    const float* __restrict__ phu, const float* __restrict__ pho,
    const float* __restrict__ zx,
    float* __restrict__ out,              // [T*B*H] outs, [B*H] hx, [B*H] cx
    unsigned long long* __restrict__ gs)  // [2][B_DIM*4] tagged gates
{
    __shared__ float Wl[NG][RPAD];     // W h-part, chunked layout
    __shared__ float hxl[ROWS][RPAD];
    __shared__ float cxl[ROWS][RPAD];
    const int tid = threadIdx.x;
    const int blk = blockIdx.x;

    // stage W h-part (cols 256..511), chunked: dst = chunk*CH + within
    for (int e = tid; e < NG * 64; e += 256) {
        int row = e >> 6, c4 = (e & 63) * 4;
        int g = row >> 2, jj = row & 3;
        const float* W = (g == 0) ? Wf : (g == 1) ? Wi : (g == 2) ? Wu : Wo;
        int dst = (c4 >> 6) * CH + (c4 & 63);
        *(float4*)&Wl[row][dst] = *(const float4*)(W + jj * DH + 256 + c4);
    }
    for (int e = tid; e < ROWS * RPAD; e += 256) {
        ((float*)hxl)[e] = 0.0f;
        ((float*)cxl)[e] = 0.0f;
    }

    // phase-1 identity: tid = r1(2b) | ks(2b) | q(4b); wave w <-> gate w
    const int r1   = tid & 3;
    const int ks   = (tid >> 2) & 3;
    const int q    = tid >> 4;            // 0..15 = gate*4 + j
    const int gate = q >> 2, j = q & 3;
    const int row_g = blk * ROWS + r1;
    const float* phiP = (gate == 0) ? phf : (gate == 1) ? phi : (gate == 2) ? phu : pho;
    const float phi_q = phiP[j];
    // phase-2 identity: thread <-> hidden column; handles all 4 owned rows
    const int col  = tid;
    const int coff = (col >> 6) * CH + (col & 63);   // chunked column offset

    __syncthreads();

    float zx_next = zx[(long)row_g * NG + q];  // prefetch t=0

    for (int t = 0; t < T_DIM; ++t) {
        const int slot = t & 1;
        const unsigned want = (unsigned)(t + 1);

        // ---- phase 1: z = zx + hx . Wh  (row r1, output q, k-chunk ks)
        float acc = 0.0f;
        #pragma unroll
        for (int i = 0; i < 16; ++i) {
            float4 h4 = *(float4*)&hxl[r1][ks * CH + i * 4];
            float4 w4 = *(float4*)&Wl[q][ks * CH + i * 4];
            acc += h4.x * w4.x + h4.y * w4.y + h4.z * w4.z + h4.w * w4.w;
        }
        acc += __shfl_xor(acc, 4);   // reduce ks (lane bits 2,3)
        acc += __shfl_xor(acc, 8);
        const float z = zx_next + acc;
        float c = (j == 0) ? 1.0f : __cosf(z + phi_q);
        float p = c * __shfl_xor(c, 16);   // product over j (lane bits 4,5)
        p = p * __shfl_xor(p, 32);
        const float gv = (gate == 2) ? fast_tanh(p) : fast_sigmoid(p);

        // publish immediately: one b64 = (tag<<32)|value, relaxed agent atomic
        if ((tid & 60) == 0) {   // ks==0 && j==0: lanes 0..3 of each wave
            unsigned long long pk =
                ((unsigned long long)want << 32) | (unsigned long long)__float_as_uint(gv);
            __hip_atomic_store(&gs[(slot << 10) + (row_g << 2) + gate], pk,
                               __ATOMIC_RELAXED, __HIP_MEMORY_SCOPE_AGENT);
        }

        // prefetch next zx (overlaps the poll)
        const int tn = (t + 1 < T_DIM) ? (t + 1) : t;
        zx_next = zx[((long)tn * B_DIM + row_g) * NG + q];

        // ---- phase 2: poll this column's 4 tagged gate words directly
        unsigned long long* gp = gs + (slot << 10) + (col << 2);
        unsigned long long v0 = __hip_atomic_load(gp + 0, __ATOMIC_RELAXED, __HIP_MEMORY_SCOPE_AGENT);
        unsigned long long v1 = __hip_atomic_load(gp + 1, __ATOMIC_RELAXED, __HIP_MEMORY_SCOPE_AGENT);
        unsigned long long v2 = __hip_atomic_load(gp + 2, __ATOMIC_RELAXED, __HIP_MEMORY_SCOPE_AGENT);
        unsigned long long v3 = __hip_atomic_load(gp + 3, __ATOMIC_RELAXED, __HIP_MEMORY_SCOPE_AGENT);
        while ((unsigned)(v0 >> 32) != want)
            v0 = __hip_atomic_load(gp + 0, __ATOMIC_RELAXED, __HIP_MEMORY_SCOPE_AGENT);
        while ((unsigned)(v1 >> 32) != want)
            v1 = __hip_atomic_load(gp + 1, __ATOMIC_RELAXED, __HIP_MEMORY_SCOPE_AGENT);
        while ((unsigned)(v2 >> 32) != want)
            v2 = __hip_atomic_load(gp + 2, __ATOMIC_RELAXED, __HIP_MEMORY_SCOPE_AGENT);
        while ((unsigned)(v3 >> 32) != want)
            v3 = __hip_atomic_load(gp + 3, __ATOMIC_RELAXED, __HIP_MEMORY_SCOPE_AGENT);

        const float f_g = __uint_as_float((unsigned)v0);
        const float i_g = __uint_as_float((unsigned)v1);
        const float u_g = __uint_as_float((unsigned)v2);
        const float o_g = __uint_as_float((unsigned)v3);
        const float ig = i_g * u_g;

        #pragma unroll
        for (int r = 0; r < ROWS; ++r) {
            const float cold = cxl[r][coff];
            const float cnew = f_g * cold + ig;
            const float h = o_g * fast_tanh(cnew);
            cxl[r][coff] = cnew;
            hxl[r][coff] = h;
            out[(long)t * (B_DIM * H_DIM) + (long)(blk * ROWS + r) * H_DIM + col] = h;
        }
        __syncthreads();   // hxl/cxl visible before next phase 1
    }

    // final hx, cx tails
    const long base_h = (long)T_DIM * B_DIM * H_DIM;
    #pragma unroll
    for (int r = 0; r < ROWS; ++r) {
        out[base_h + (long)(blk * ROWS + r) * H_DIM + col] = hxl[r][coff];
        out[base_h + (long)B_DIM * H_DIM + (long)(blk * ROWS + r) * H_DIM + col] = cxl[r][coff];
    }
}

extern "C" void kernel_launch(void* const* d_in, const int* in_sizes, int n_in,
                              void* d_out, int out_size, void* d_ws, size_t ws_size,
                              hipStream_t stream) {
    (void)in_sizes; (void)n_in; (void)out_size; (void)ws_size;
    const float* x   = (const float*)d_in[0];
    const float* Wf  = (const float*)d_in[1];
    const float* bf  = (const float*)d_in[2];
    const float* phf = (const float*)d_in[3];
    const float* Wi  = (const float*)d_in[4];
    const float* bi  = (const float*)d_in[5];
    const float* phi = (const float*)d_in[6];
    const float* Wu  = (const float*)d_in[7];
    const float* bu  = (const float*)d_in[8];
    const float* phu = (const float*)d_in[9];
    const float* Wo  = (const float*)d_in[10];
    const float* bo  = (const float*)d_in[11];
    const float* pho = (const float*)d_in[12];

    float* zx = (float*)d_ws;                                  // T*B*16 floats = 8.39 MB
    unsigned long long* gs =
        (unsigned long long*)(zx + (size_t)T_DIM * B_DIM * NG); // 2*1024 u64 = 16 KB
    // no memset: poison tag 0xAAAAAAAA never equals a wanted tag (1..512)

    zx_kernel<<<(T_DIM * B_DIM) / 16, 256, 0, stream>>>(
        x, Wf, Wi, Wu, Wo, bf, bi, bu, bo, zx);

    rec_kernel<<<NB, 256, 0, stream>>>(
        Wf, Wi, Wu, Wo, phf, phi, phu, pho, zx,
        (float*)d_out, gs);
}

// Round 4
// 1685.093 us; speedup vs baseline: 2.5884x; 1.0452x over previous
//
#include <hip/hip_runtime.h>

// QuantumQLSTM on MI355X.
// zx[t,b,16] = x @ Wx^T + b precomputed (parallel); recurrent kernel: 64
// persistent blocks, 4 batch rows each; hx in LDS, cx in REGISTERS.
//
// R1: agent release/acquire fences -> L2 wb/inv each step (4250us).
// R2: relaxed LLC atomics, flag indirection -> 9.4k cyc/step (2010us).
// R3: single-word tagged gates, direct poll -> 7.1k cyc/step (1516us).
//     Post-mortem: poll was SERIALIZED (spin v0, then stale-check v1 ->
//     re-poll, ...) = ~3 extra LLC round-trips per step.
// R4: fused poll (re-load all 4 words per iteration, exit on AND of tags)
//     + cx in registers (phase-2 thread exclusively owns its column slice;
//     deletes 8 LDS ops/thread/step and the cxl array).

#define T_DIM 512
#define B_DIM 256
#define D_DIM 256
#define H_DIM 256
#define DH    512   // D + H
#define NG    16    // 4 gates * NQ(4)
#define NB    64    // persistent blocks
#define ROWS  4     // batch rows per block
#define PAD   260   // zx_kernel LDS row stride
#define CH    68    // rec LDS chunk stride: 64 floats + 4 pad (0 bank conflicts, R3)
#define RPAD  272   // rec LDS row stride = 4*CH

__device__ __forceinline__ float fast_sigmoid(float x) {
    return 1.0f / (1.0f + __expf(-x));
}
__device__ __forceinline__ float fast_tanh(float x) {
    // |x| <= ~2.1 in this model (cx contraction: f <= sigmoid(1) = 0.731)
    float e = __expf(2.0f * x);
    return (e - 1.0f) / (e + 1.0f);
}

// -------------------- zx precompute: zx[(t*B+b)*16+q] = b_q + x[t,b,:] . Wx[q,:]
__global__ __launch_bounds__(256) void zx_kernel(
    const float* __restrict__ x,
    const float* __restrict__ Wf, const float* __restrict__ Wi,
    const float* __restrict__ Wu, const float* __restrict__ Wo,
    const float* __restrict__ bf, const float* __restrict__ bi,
    const float* __restrict__ bu, const float* __restrict__ bo,
    float* __restrict__ zx)
{
    __shared__ float Wl[NG][PAD];
    __shared__ float Xl[16][PAD];
    const int tid = threadIdx.x;

    for (int e = tid; e < NG * 64; e += 256) {
        int q16 = e >> 6, c4 = (e & 63) * 4;
        int g = q16 >> 2, qj = q16 & 3;
        const float* W = (g == 0) ? Wf : (g == 1) ? Wi : (g == 2) ? Wu : Wo;
        *(float4*)&Wl[q16][c4] = *(const float4*)(W + qj * DH + c4);
    }
    const long base = (long)blockIdx.x * 16 * D_DIM;
    for (int e = tid; e < 16 * 64; e += 256) {
        int r = e >> 6, c4 = (e & 63) * 4;
        *(float4*)&Xl[r][c4] = *(const float4*)(x + base + r * D_DIM + c4);
    }
    __syncthreads();

    const int q16 = tid & 15, r = tid >> 4;
    const int g = q16 >> 2, qj = q16 & 3;
    const float* bv = (g == 0) ? bf : (g == 1) ? bi : (g == 2) ? bu : bo;
    float acc = bv[qj];
    #pragma unroll 4
    for (int k = 0; k < D_DIM; k += 4) {
        float4 xv = *(float4*)&Xl[r][k];
        float4 wv = *(float4*)&Wl[q16][k];
        acc += xv.x * wv.x + xv.y * wv.y + xv.z * wv.z + xv.w * wv.w;
    }
    zx[(long)blockIdx.x * 256 + tid] = acc;
}

// -------------------- recurrent kernel
__global__ __launch_bounds__(256) void rec_kernel(
    const float* __restrict__ Wf, const float* __restrict__ Wi,
    const float* __restrict__ Wu, const float* __restrict__ Wo,
    const float* __restrict__ phf, const float* __restrict__ phi,
    const float* __restrict__ phu, const float* __restrict__ pho,
    const float* __restrict__ zx,
    float* __restrict__ out,              // [T*B*H] outs, [B*H] hx, [B*H] cx
    unsigned long long* __restrict__ gs)  // [2][B_DIM*4] tagged gates
{
    __shared__ float Wl[NG][RPAD];     // W h-part, chunked layout
    __shared__ float hxl[ROWS][RPAD];
    const int tid = threadIdx.x;
    const int blk = blockIdx.x;

    // stage W h-part (cols 256..511), chunked: dst = chunk*CH + within
    for (int e = tid; e < NG * 64; e += 256) {
        int row = e >> 6, c4 = (e & 63) * 4;
        int g = row >> 2, jj = row & 3;
        const float* W = (g == 0) ? Wf : (g == 1) ? Wi : (g == 2) ? Wu : Wo;
        int dst = (c4 >> 6) * CH + (c4 & 63);
        *(float4*)&Wl[row][dst] = *(const float4*)(W + jj * DH + 256 + c4);
    }
    for (int e = tid; e < ROWS * RPAD; e += 256) {
        ((float*)hxl)[e] = 0.0f;
    }

    // phase-1 identity: tid = r1(2b) | ks(2b) | q(4b); wave w <-> gate w
    const int r1   = tid & 3;
    const int ks   = (tid >> 2) & 3;
    const int q    = tid >> 4;            // 0..15 = gate*4 + j
    const int gate = q >> 2, j = q & 3;
    const int row_g = blk * ROWS + r1;
    const float* phiP = (gate == 0) ? phf : (gate == 1) ? phi : (gate == 2) ? phu : pho;
    const float phi_q = phiP[j];
    // phase-2 identity: thread <-> hidden column; owns all 4 rows of that column
    const int col  = tid;
    const int coff = (col >> 6) * CH + (col & 63);   // chunked column offset

    // cx lives in registers: this thread exclusively owns column `col`
    // of rows blk*4 .. blk*4+3.
    float creg[ROWS] = {0.0f, 0.0f, 0.0f, 0.0f};

    __syncthreads();

    float zx_next = zx[(long)row_g * NG + q];  // prefetch t=0

    for (int t = 0; t < T_DIM; ++t) {
        const int slot = t & 1;
        const unsigned want = (unsigned)(t + 1);

        // ---- phase 1: z = zx + hx . Wh  (row r1, output q, k-chunk ks)
        float acc = 0.0f;
        #pragma unroll
        for (int i = 0; i < 16; ++i) {
            float4 h4 = *(float4*)&hxl[r1][ks * CH + i * 4];
            float4 w4 = *(float4*)&Wl[q][ks * CH + i * 4];
            acc += h4.x * w4.x + h4.y * w4.y + h4.z * w4.z + h4.w * w4.w;
        }
        acc += __shfl_xor(acc, 4);   // reduce ks (lane bits 2,3)
        acc += __shfl_xor(acc, 8);
        const float z = zx_next + acc;
        float c = (j == 0) ? 1.0f : __cosf(z + phi_q);
        float p = c * __shfl_xor(c, 16);   // product over j (lane bits 4,5)
        p = p * __shfl_xor(p, 32);
        const float gv = (gate == 2) ? fast_tanh(p) : fast_sigmoid(p);

        // publish immediately: one b64 = (tag<<32)|value, relaxed agent atomic
        if ((tid & 60) == 0) {   // ks==0 && j==0: lanes 0..3 of each wave
            unsigned long long pk =
                ((unsigned long long)want << 32) | (unsigned long long)__float_as_uint(gv);
            __hip_atomic_store(&gs[(slot << 10) + (row_g << 2) + gate], pk,
                               __ATOMIC_RELAXED, __HIP_MEMORY_SCOPE_AGENT);
        }

        // prefetch next zx (overlaps the poll)
        const int tn = (t + 1 < T_DIM) ? (t + 1) : t;
        zx_next = zx[((long)tn * B_DIM + row_g) * NG + q];

        // ---- phase 2: FUSED poll of this column's 4 tagged words
        // (re-load all four every iteration; exit on AND of tags — no serial
        //  stale-check chains, worst case ~1 extra LLC RT total)
        unsigned long long* gp = gs + (slot << 10) + (col << 2);
        unsigned long long v0, v1, v2, v3;
        for (;;) {
            v0 = __hip_atomic_load(gp + 0, __ATOMIC_RELAXED, __HIP_MEMORY_SCOPE_AGENT);
            v1 = __hip_atomic_load(gp + 1, __ATOMIC_RELAXED, __HIP_MEMORY_SCOPE_AGENT);
            v2 = __hip_atomic_load(gp + 2, __ATOMIC_RELAXED, __HIP_MEMORY_SCOPE_AGENT);
            v3 = __hip_atomic_load(gp + 3, __ATOMIC_RELAXED, __HIP_MEMORY_SCOPE_AGENT);
            bool ok = ((unsigned)(v0 >> 32) == want) &
                      ((unsigned)(v1 >> 32) == want) &
                      ((unsigned)(v2 >> 32) == want) &
                      ((unsigned)(v3 >> 32) == want);
            if (ok) break;
        }

        const float f_g = __uint_as_float((unsigned)v0);
        const float i_g = __uint_as_float((unsigned)v1);
        const float u_g = __uint_as_float((unsigned)v2);
        const float o_g = __uint_as_float((unsigned)v3);
        const float ig = i_g * u_g;

        #pragma unroll
        for (int r = 0; r < ROWS; ++r) {
            const float cnew = f_g * creg[r] + ig;
            const float h = o_g * fast_tanh(cnew);
            creg[r] = cnew;
            hxl[r][coff] = h;
            out[(long)t * (B_DIM * H_DIM) + (long)(blk * ROWS + r) * H_DIM + col] = h;
        }
        __syncthreads();   // hxl visible before next phase 1
    }

    // final hx, cx tails
    const long base_h = (long)T_DIM * B_DIM * H_DIM;
    #pragma unroll
    for (int r = 0; r < ROWS; ++r) {
        out[base_h + (long)(blk * ROWS + r) * H_DIM + col] = hxl[r][coff];
        out[base_h + (long)B_DIM * H_DIM + (long)(blk * ROWS + r) * H_DIM + col] = creg[r];
    }
}

extern "C" void kernel_launch(void* const* d_in, const int* in_sizes, int n_in,
                              void* d_out, int out_size, void* d_ws, size_t ws_size,
                              hipStream_t stream) {
    (void)in_sizes; (void)n_in; (void)out_size; (void)ws_size;
    const float* x   = (const float*)d_in[0];
    const float* Wf  = (const float*)d_in[1];
    const float* bf  = (const float*)d_in[2];
    const float* phf = (const float*)d_in[3];
    const float* Wi  = (const float*)d_in[4];
    const float* bi  = (const float*)d_in[5];
    const float* phi = (const float*)d_in[6];
    const float* Wu  = (const float*)d_in[7];
    const float* bu  = (const float*)d_in[8];
    const float* phu = (const float*)d_in[9];
    const float* Wo  = (const float*)d_in[10];
    const float* bo  = (const float*)d_in[11];
    const float* pho = (const float*)d_in[12];

    float* zx = (float*)d_ws;                                  // T*B*16 floats = 8.39 MB
    unsigned long long* gs =
        (unsigned long long*)(zx + (size_t)T_DIM * B_DIM * NG); // 2*1024 u64 = 16 KB
    // no memset: poison tag 0xAAAAAAAA never equals a wanted tag (1..512)

    zx_kernel<<<(T_DIM * B_DIM) / 16, 256, 0, stream>>>(
        x, Wf, Wi, Wu, Wo, bf, bi, bu, bo, zx);

    rec_kernel<<<NB, 256, 0, stream>>>(
        Wf, Wi, Wu, Wo, phf, phi, phu, pho, zx,
        (float*)d_out, gs);
}

// Round 5
// 1425.596 us; speedup vs baseline: 3.0595x; 1.1820x over previous
//
#include <hip/hip_runtime.h>

// QuantumQLSTM on MI355X.
// zx precomputed; recurrent kernel: 64 persistent blocks, 4 batch rows each;
// hx in LDS, cx in registers; cross-block exchange = ONE tagged u64 per row.
//
// R1: agent release/acquire fences -> L2 wb/inv each step (4250us).
// R2: relaxed LLC atomics, flag indirection -> 9.4k cyc/step (2010us).
// R3: tagged per-gate words, serialized poll -> 7.1k cyc/step (1516us).
// R4: fused 4-word poll + cx in regs -> 6.8k cyc/step (1443us). Post-mortem:
//     4-word poll was NOT the cost; residual = detect quantization (RT-sized
//     poll iterations) x max-over-4-publishers x max-over-64-blocks + barrier
//     vmcnt drains of out-store acks.
// R5: (a) pack 4 gates (14-bit quant) + 8-bit tag into ONE u64 per row via
//     small LDS gather (+1 intra-block barrier); consumers poll ONE word ->
//     single publisher, single-RT detect, 4x less poll traffic.
//     (b) out[] stores issue AFTER the end-of-step barrier -> their acks
//     drain during next phase-1, off the critical path.

#define T_DIM 512
#define B_DIM 256
#define D_DIM 256
#define H_DIM 256
#define DH    512   // D + H
#define NG    16    // 4 gates * NQ(4)
#define NB    64    // persistent blocks
#define ROWS  4     // batch rows per block
#define PAD   260   // zx_kernel LDS row stride
#define CH    68    // rec LDS chunk stride: 64 floats + 4 pad (0 bank conflicts)
#define RPAD  272   // rec LDS row stride = 4*CH

__device__ __forceinline__ float fast_sigmoid(float x) {
    return 1.0f / (1.0f + __expf(-x));
}
__device__ __forceinline__ float fast_tanh(float x) {
    // |x| <= ~2.1 in this model (cx contraction: f <= sigmoid(1) = 0.731)
    float e = __expf(2.0f * x);
    return (e - 1.0f) / (e + 1.0f);
}
// 14-bit quantize of v in (-1,1): err <= 1.2e-4
__device__ __forceinline__ unsigned long long quant14(float v) {
    int e = (int)((v + 1.0f) * 8192.0f + 0.5f);
    e = e < 0 ? 0 : (e > 16383 ? 16383 : e);
    return (unsigned long long)e;
}
__device__ __forceinline__ float dequant14(unsigned long long w, int sh) {
    return fmaf((float)((unsigned)(w >> sh) & 16383u), 1.0f / 8192.0f, -1.0f);
}

// -------------------- zx precompute: zx[(t*B+b)*16+q] = b_q + x[t,b,:] . Wx[q,:]
__global__ __launch_bounds__(256) void zx_kernel(
    const float* __restrict__ x,
    const float* __restrict__ Wf, const float* __restrict__ Wi,
    const float* __restrict__ Wu, const float* __restrict__ Wo,
    const float* __restrict__ bf, const float* __restrict__ bi,
    const float* __restrict__ bu, const float* __restrict__ bo,
    float* __restrict__ zx)
{
    __shared__ float Wl[NG][PAD];
    __shared__ float Xl[16][PAD];
    const int tid = threadIdx.x;

    for (int e = tid; e < NG * 64; e += 256) {
        int q16 = e >> 6, c4 = (e & 63) * 4;
        int g = q16 >> 2, qj = q16 & 3;
        const float* W = (g == 0) ? Wf : (g == 1) ? Wi : (g == 2) ? Wu : Wo;
        *(float4*)&Wl[q16][c4] = *(const float4*)(W + qj * DH + c4);
    }
    const long base = (long)blockIdx.x * 16 * D_DIM;
    for (int e = tid; e < 16 * 64; e += 256) {
        int r = e >> 6, c4 = (e & 63) * 4;
        *(float4*)&Xl[r][c4] = *(const float4*)(x + base + r * D_DIM + c4);
    }
    __syncthreads();

    const int q16 = tid & 15, r = tid >> 4;
    const int g = q16 >> 2, qj = q16 & 3;
    const float* bv = (g == 0) ? bf : (g == 1) ? bi : (g == 2) ? bu : bo;
    float acc = bv[qj];
    #pragma unroll 4
    for (int k = 0; k < D_DIM; k += 4) {
        float4 xv = *(float4*)&Xl[r][k];
        float4 wv = *(float4*)&Wl[q16][k];
        acc += xv.x * wv.x + xv.y * wv.y + xv.z * wv.z + xv.w * wv.w;
    }
    zx[(long)blockIdx.x * 256 + tid] = acc;
}

// -------------------- recurrent kernel
__global__ __launch_bounds__(256) void rec_kernel(
    const float* __restrict__ Wf, const float* __restrict__ Wi,
    const float* __restrict__ Wu, const float* __restrict__ Wo,
    const float* __restrict__ phf, const float* __restrict__ phi,
    const float* __restrict__ phu, const float* __restrict__ pho,
    const float* __restrict__ zx,
    float* __restrict__ out,              // [T*B*H] outs, [B*H] hx, [B*H] cx
    unsigned long long* __restrict__ gs)  // [2][B_DIM] packed tagged gates
{
    __shared__ float Wl[NG][RPAD];     // W h-part, chunked layout
    __shared__ float hxl[ROWS][RPAD];
    __shared__ __align__(16) float gpack[ROWS][4];  // gate gather: [row][gate]
    const int tid = threadIdx.x;
    const int blk = blockIdx.x;

    // stage W h-part (cols 256..511), chunked: dst = chunk*CH + within
    for (int e = tid; e < NG * 64; e += 256) {
        int row = e >> 6, c4 = (e & 63) * 4;
        int g = row >> 2, jj = row & 3;
        const float* W = (g == 0) ? Wf : (g == 1) ? Wi : (g == 2) ? Wu : Wo;
        int dst = (c4 >> 6) * CH + (c4 & 63);
        *(float4*)&Wl[row][dst] = *(const float4*)(W + jj * DH + 256 + c4);
    }
    for (int e = tid; e < ROWS * RPAD; e += 256) {
        ((float*)hxl)[e] = 0.0f;
    }

    // phase-1 identity: tid = r1(2b) | ks(2b) | q(4b); wave w <-> gate w
    const int r1   = tid & 3;
    const int ks   = (tid >> 2) & 3;
    const int q    = tid >> 4;            // 0..15 = gate*4 + j
    const int gate = q >> 2, j = q & 3;
    const int row_g = blk * ROWS + r1;
    const float* phiP = (gate == 0) ? phf : (gate == 1) ? phi : (gate == 2) ? phu : pho;
    const float phi_q = phiP[j];
    // phase-2 identity: thread <-> hidden column; owns all 4 rows of that column
    const int col  = tid;
    const int coff = (col >> 6) * CH + (col & 63);   // chunked column offset

    // cx in registers: this thread exclusively owns column `col` of its 4 rows
    float creg[ROWS] = {0.0f, 0.0f, 0.0f, 0.0f};
    float harr[ROWS] = {0.0f, 0.0f, 0.0f, 0.0f};

    __syncthreads();

    float zx_next = zx[(long)row_g * NG + q];  // prefetch t=0

    for (int t = 0; t < T_DIM; ++t) {
        const int slot = t & 1;
        const unsigned wantb = (unsigned)((t + 1) & 255);

        // ---- phase 1: z = zx + hx . Wh  (row r1, output q, k-chunk ks)
        float acc = 0.0f;
        #pragma unroll
        for (int i = 0; i < 16; ++i) {
            float4 h4 = *(float4*)&hxl[r1][ks * CH + i * 4];
            float4 w4 = *(float4*)&Wl[q][ks * CH + i * 4];
            acc += h4.x * w4.x + h4.y * w4.y + h4.z * w4.z + h4.w * w4.w;
        }
        acc += __shfl_xor(acc, 4);   // reduce ks (lane bits 2,3)
        acc += __shfl_xor(acc, 8);
        const float z = zx_next + acc;
        float c = (j == 0) ? 1.0f : __cosf(z + phi_q);
        float p = c * __shfl_xor(c, 16);   // product over j (lane bits 4,5)
        p = p * __shfl_xor(p, 32);
        const float gv = (gate == 2) ? fast_tanh(p) : fast_sigmoid(p);

        // gather the 4 gates of each row into LDS (16 writers, distinct cells)
        if ((tid & 60) == 0) {   // ks==0 && j==0
            gpack[r1][gate] = gv;
        }
        __syncthreads();   // pack barrier (also drains prev-step out-store acks)

        // publish: ONE tagged u64 per row (threads 0..3)
        if (tid < ROWS) {
            float4 g4 = *(float4*)gpack[tid];   // x=f, y=i, z=update, w=o
            unsigned long long w =
                ((unsigned long long)wantb << 56) |
                (quant14(g4.x) << 42) | (quant14(g4.y) << 28) |
                (quant14(g4.z) << 14) |  quant14(g4.w);
            __hip_atomic_store(&gs[(slot << 8) + blk * ROWS + tid], w,
                               __ATOMIC_RELAXED, __HIP_MEMORY_SCOPE_AGENT);
        }

        // prefetch next zx (overlaps the poll; issued after the barrier so the
        // barrier's vmcnt drain doesn't wait on it)
        const int tn = (t + 1 < T_DIM) ? (t + 1) : t;
        zx_next = zx[((long)tn * B_DIM + row_g) * NG + q];

        // ---- phase 2: poll ONE packed word for this column's row
        unsigned long long* gp = gs + (slot << 8) + col;
        unsigned long long v;
        do {
            v = __hip_atomic_load(gp, __ATOMIC_RELAXED, __HIP_MEMORY_SCOPE_AGENT);
        } while ((unsigned)(v >> 56) != wantb);

        const float f_g = dequant14(v, 42);
        const float i_g = dequant14(v, 28);
        const float u_g = dequant14(v, 14);
        const float o_g = dequant14(v, 0);
        const float ig = i_g * u_g;

        #pragma unroll
        for (int r = 0; r < ROWS; ++r) {
            const float cnew = f_g * creg[r] + ig;
            const float h = o_g * fast_tanh(cnew);
            creg[r] = cnew;
            harr[r] = h;
            hxl[r][coff] = h;
        }
        __syncthreads();   // hxl visible before next phase 1

        // out stores AFTER the barrier: acks drain during next phase-1
        #pragma unroll
        for (int r = 0; r < ROWS; ++r) {
            out[(long)t * (B_DIM * H_DIM) + (long)(blk * ROWS + r) * H_DIM + col] = harr[r];
        }
    }

    // final hx, cx tails
    const long base_h = (long)T_DIM * B_DIM * H_DIM;
    #pragma unroll
    for (int r = 0; r < ROWS; ++r) {
        out[base_h + (long)(blk * ROWS + r) * H_DIM + col] = harr[r];
        out[base_h + (long)B_DIM * H_DIM + (long)(blk * ROWS + r) * H_DIM + col] = creg[r];
    }
}

extern "C" void kernel_launch(void* const* d_in, const int* in_sizes, int n_in,
                              void* d_out, int out_size, void* d_ws, size_t ws_size,
                              hipStream_t stream) {
    (void)in_sizes; (void)n_in; (void)out_size; (void)ws_size;
    const float* x   = (const float*)d_in[0];
    const float* Wf  = (const float*)d_in[1];
    const float* bf  = (const float*)d_in[2];
    const float* phf = (const float*)d_in[3];
    const float* Wi  = (const float*)d_in[4];
    const float* bi  = (const float*)d_in[5];
    const float* phi = (const float*)d_in[6];
    const float* Wu  = (const float*)d_in[7];
    const float* bu  = (const float*)d_in[8];
    const float* phu = (const float*)d_in[9];
    const float* Wo  = (const float*)d_in[10];
    const float* bo  = (const float*)d_in[11];
    const float* pho = (const float*)d_in[12];

    float* zx = (float*)d_ws;                                  // T*B*16 floats = 8.39 MB
    unsigned long long* gs =
        (unsigned long long*)(zx + (size_t)T_DIM * B_DIM * NG); // 2*256 u64 = 4 KB
    // no memset: poison tag byte 0xAA(=170) only exists before the first write
    // of each slot, where wanted tags are 1 and 2.

    zx_kernel<<<(T_DIM * B_DIM) / 16, 256, 0, stream>>>(
        x, Wf, Wi, Wu, Wo, bf, bi, bu, bo, zx);

    rec_kernel<<<NB, 256, 0, stream>>>(
        Wf, Wi, Wu, Wo, phf, phi, phu, pho, zx,
        (float*)d_out, gs);
}

// Round 7
// 758.575 us; speedup vs baseline: 5.7498x; 1.8793x over previous
//
#include <hip/hip_runtime.h>

// QuantumQLSTM on MI355X — R7: structural collapse.
// The [B]*[B,H] broadcast makes gates column-indexed: cx[b,h] = f[h]*cx[b,h]
// + i[h]*g[h]. With cx(0)=0, cx and hx are INDEPENDENT OF b: every batch row
// carries the same hidden vector Hv[h,t]. So:
//   - recurrent projection zh[t] = Wh . Hv[t-1]: ONE 16x256 matvec/step
//   - gates per row h: from zx[t,h,:] + zh[t]
//   - outs[t,b,h] = Hv[h,t]  -> 134 MB output is a broadcast of a 512 KB table
// Pipeline: zx precompute (parallel) -> single-block sequential rec (writes
// Hv table + final C) -> broadcast kernel (write-roofline).
//
// History: R1 fences 4250us -> R2 relaxed LLC 2010 -> R3 tagged 1516 ->
// R4 fused poll 1443 -> R5 packed u64 1426 -> R6 FAILED (misread broadcast)
// -> R7 rank-collapse.

#define T_DIM 512
#define B_DIM 256
#define D_DIM 256
#define H_DIM 256
#define DH    512   // D + H
#define NG    16    // 4 gates * NQ(4)
#define PAD   260   // zx LDS row stride

__device__ __forceinline__ float fast_sigmoid(float x) {
    return 1.0f / (1.0f + __expf(-x));
}
__device__ __forceinline__ float fast_tanh(float x) {
    // |x| <= ~2.1 here (|C| <= 0.557/(1-0.731)); exp safe
    float e = __expf(2.0f * x);
    return (e - 1.0f) / (e + 1.0f);
}

// -------------------- zx precompute: zx[(t*B+b)*16+q] = b_q + x[t,b,:].Wx[q,:]
// (verified R1-R5 kernel, unchanged)
__global__ __launch_bounds__(256) void zx_kernel(
    const float* __restrict__ x,
    const float* __restrict__ Wf, const float* __restrict__ Wi,
    const float* __restrict__ Wu, const float* __restrict__ Wo,
    const float* __restrict__ bf, const float* __restrict__ bi,
    const float* __restrict__ bu, const float* __restrict__ bo,
    float* __restrict__ zx)
{
    __shared__ float Wl[NG][PAD];
    __shared__ float Xl[16][PAD];
    const int tid = threadIdx.x;

    for (int e = tid; e < NG * 64; e += 256) {
        int q16 = e >> 6, c4 = (e & 63) * 4;
        int g = q16 >> 2, qj = q16 & 3;
        const float* W = (g == 0) ? Wf : (g == 1) ? Wi : (g == 2) ? Wu : Wo;
        *(float4*)&Wl[q16][c4] = *(const float4*)(W + qj * DH + c4);
    }
    const long base = (long)blockIdx.x * 16 * D_DIM;
    for (int e = tid; e < 16 * 64; e += 256) {
        int r = e >> 6, c4 = (e & 63) * 4;
        *(float4*)&Xl[r][c4] = *(const float4*)(x + base + r * D_DIM + c4);
    }
    __syncthreads();

    const int q16 = tid & 15, r = tid >> 4;
    const int g = q16 >> 2, qj = q16 & 3;
    const float* bv = (g == 0) ? bf : (g == 1) ? bi : (g == 2) ? bu : bo;
    float acc = bv[qj];
    #pragma unroll 4
    for (int k = 0; k < D_DIM; k += 4) {
        float4 xv = *(float4*)&Xl[r][k];
        float4 wv = *(float4*)&Wl[q16][k];
        acc += xv.x * wv.x + xv.y * wv.y + xv.z * wv.z + xv.w * wv.w;
    }
    zx[(long)blockIdx.x * 256 + tid] = acc;
}

// -------------------- sequential core: ONE block, 256 threads.
// Wave 0: zh = Wh . Hv (lane=(q,ks), Wh slice in regs). All threads: row h=tid
// gates + state update. Hv in LDS; C in a register. Writes Hv[t] table + final C.
__global__ __launch_bounds__(256) void rec_kernel(
    const float* __restrict__ Wf, const float* __restrict__ Wi,
    const float* __restrict__ Wu, const float* __restrict__ Wo,
    const float* __restrict__ phf, const float* __restrict__ phi,
    const float* __restrict__ phu, const float* __restrict__ pho,
    const float* __restrict__ zx,
    float* __restrict__ hv_tab,   // [T][H]
    float* __restrict__ c_fin)    // [H]
{
    __shared__ float Hs[H_DIM];
    __shared__ float zh_s[NG];
    const int tid = threadIdx.x;

    // wave-0 matvec identity
    const int lane = tid & 63;
    const int q = lane >> 2, ks = lane & 3;
    const int gate = q >> 2, j = q & 3;
    float4 Wreg[16];
    if (tid < 64) {
        const float* Wb = (gate == 0) ? Wf : (gate == 1) ? Wi : (gate == 2) ? Wu : Wo;
        const float* Wr = Wb + j * DH + 256 + ks * 64;   // h-part cols
        #pragma unroll
        for (int i = 0; i < 16; ++i) Wreg[i] = ((const float4*)Wr)[i];
    }
    // per-thread phases
    const float pf1 = phf[1], pf2 = phf[2], pf3 = phf[3];
    const float pi1 = phi[1], pi2 = phi[2], pi3 = phi[3];
    const float pu1 = phu[1], pu2 = phu[2], pu3 = phu[3];
    const float po1 = pho[1], po2 = pho[2], po3 = pho[3];

    float C = 0.0f;
    Hs[tid] = 0.0f;
    __syncthreads();

    // zx prefetch pipeline, depth 2 (register double-buffer, loop unroll x2)
    float4 za[4], zb[4];
    {
        const float4* p0 = (const float4*)(zx + (long)tid * NG);
        const float4* p1 = (const float4*)(zx + ((long)B_DIM + tid) * NG);
        #pragma unroll
        for (int i = 0; i < 4; ++i) { za[i] = p0[i]; zb[i] = p1[i]; }
    }

    auto step = [&](int t, float4* zr) {
        // ---- A: zh = Wh . Hv (wave 0)
        if (tid < 64) {
            float a0 = 0.f, a1 = 0.f, a2 = 0.f, a3 = 0.f;
            #pragma unroll
            for (int i = 0; i < 4; ++i) {
                float4 h0 = *(float4*)&Hs[ks * 64 + i * 16 + 0];
                float4 h1 = *(float4*)&Hs[ks * 64 + i * 16 + 4];
                float4 h2 = *(float4*)&Hs[ks * 64 + i * 16 + 8];
                float4 h3 = *(float4*)&Hs[ks * 64 + i * 16 + 12];
                float4 w0 = Wreg[i * 4 + 0], w1 = Wreg[i * 4 + 1];
                float4 w2 = Wreg[i * 4 + 2], w3 = Wreg[i * 4 + 3];
                a0 = fmaf(h0.x, w0.x, fmaf(h0.y, w0.y, fmaf(h0.z, w0.z, fmaf(h0.w, w0.w, a0))));
                a1 = fmaf(h1.x, w1.x, fmaf(h1.y, w1.y, fmaf(h1.z, w1.z, fmaf(h1.w, w1.w, a1))));
                a2 = fmaf(h2.x, w2.x, fmaf(h2.y, w2.y, fmaf(h2.z, w2.z, fmaf(h2.w, w2.w, a2))));
                a3 = fmaf(h3.x, w3.x, fmaf(h3.y, w3.y, fmaf(h3.z, w3.z, fmaf(h3.w, w3.w, a3))));
            }
            float acc = (a0 + a1) + (a2 + a3);
            acc += __shfl_xor(acc, 1);   // reduce ks (lane bits 0,1)
            acc += __shfl_xor(acc, 2);
            if (ks == 0) zh_s[q] = acc;
        }
        __syncthreads();

        // ---- B: row h = tid
        float4 zh0 = ((float4*)zh_s)[0], zh1 = ((float4*)zh_s)[1];
        float4 zh2 = ((float4*)zh_s)[2], zh3 = ((float4*)zh_s)[3];
        const float z1  = zr[0].y + zh0.y, z2  = zr[0].z + zh0.z, z3  = zr[0].w + zh0.w;
        const float z5  = zr[1].y + zh1.y, z6  = zr[1].z + zh1.z, z7  = zr[1].w + zh1.w;
        const float z9  = zr[2].y + zh2.y, z10 = zr[2].z + zh2.z, z11 = zr[2].w + zh2.w;
        const float z13 = zr[3].y + zh3.y, z14 = zr[3].z + zh3.z, z15 = zr[3].w + zh3.w;

        // prefetch zx for t+2 into the buffer just consumed
        {
            const int tp = (t + 2 < T_DIM) ? (t + 2) : t;
            const float4* pp = (const float4*)(zx + ((long)tp * B_DIM + tid) * NG);
            #pragma unroll
            for (int i = 0; i < 4; ++i) zr[i] = pp[i];
        }

        const float pf = __cosf(z1 + pf1) * __cosf(z2 + pf2) * __cosf(z3 + pf3);
        const float pi_ = __cosf(z5 + pi1) * __cosf(z6 + pi2) * __cosf(z7 + pi3);
        const float pu = __cosf(z9 + pu1) * __cosf(z10 + pu2) * __cosf(z11 + pu3);
        const float po = __cosf(z13 + po1) * __cosf(z14 + po2) * __cosf(z15 + po3);
        const float f  = fast_sigmoid(pf);
        const float ii = fast_sigmoid(pi_);
        const float u  = fast_tanh(pu);
        const float o  = fast_sigmoid(po);
        C = fmaf(f, C, ii * u);
        const float Hnew = o * fast_tanh(C);

        Hs[tid] = Hnew;                       // for next step's matvec
        hv_tab[(long)t * H_DIM + tid] = Hnew; // table for broadcast kernel
        __syncthreads();
    };

    for (int t = 0; t < T_DIM; t += 2) {
        step(t, za);
        step(t + 1, zb);
    }
    c_fin[tid] = C;
}

// -------------------- broadcast: out[t,b,:] = Hv[t,:]; tails hx=Hv[511], cx=Cfin
// block<2048: t=blk>>2, rows (blk&3)*64..+63. Each wave: one float4 column
// chunk, stored to 16 rows (1KB contiguous per wave-row -> fully coalesced).
__global__ __launch_bounds__(256) void bc_kernel(
    const float* __restrict__ hv_tab, const float* __restrict__ c_fin,
    float* __restrict__ out)
{
    const int blk  = blockIdx.x;
    const int w    = threadIdx.x >> 6;
    const int lane = threadIdx.x & 63;

    const float* src;
    long base;
    int rbase;
    if (blk < 4 * T_DIM) {
        const int t = blk >> 2;
        rbase = (blk & 3) * 64;
        src = hv_tab + (long)t * H_DIM;
        base = (long)t * (B_DIM * H_DIM);
    } else {
        const int k = blk - 4 * T_DIM;        // 0..7
        rbase = (k & 3) * 64;
        src = (k < 4) ? (hv_tab + (long)(T_DIM - 1) * H_DIM) : c_fin;
        base = (long)T_DIM * (B_DIM * H_DIM) + (k < 4 ? 0 : (long)B_DIM * H_DIM);
    }
    const float4 v = ((const float4*)src)[lane];
    #pragma unroll
    for (int it = 0; it < 16; ++it) {
        const int row = rbase + w + 4 * it;
        ((float4*)(out + base + (long)row * H_DIM))[lane] = v;
    }
}

extern "C" void kernel_launch(void* const* d_in, const int* in_sizes, int n_in,
                              void* d_out, int out_size, void* d_ws, size_t ws_size,
                              hipStream_t stream) {
    (void)in_sizes; (void)n_in; (void)out_size; (void)ws_size;
    const float* x   = (const float*)d_in[0];
    const float* Wf  = (const float*)d_in[1];
    const float* bf  = (const float*)d_in[2];
    const float* phf = (const float*)d_in[3];
    const float* Wi  = (const float*)d_in[4];
    const float* bi  = (const float*)d_in[5];
    const float* phi = (const float*)d_in[6];
    const float* Wu  = (const float*)d_in[7];
    const float* bu  = (const float*)d_in[8];
    const float* phu = (const float*)d_in[9];
    const float* Wo  = (const float*)d_in[10];
    const float* bo  = (const float*)d_in[11];
    const float* pho = (const float*)d_in[12];

    float* zx     = (float*)d_ws;                              // T*B*16 f = 8.39 MB
    float* hv_tab = zx + (size_t)T_DIM * B_DIM * NG;           // T*H f = 512 KB
    float* c_fin  = hv_tab + (size_t)T_DIM * H_DIM;            // H f = 1 KB

    zx_kernel<<<(T_DIM * B_DIM) / 16, 256, 0, stream>>>(
        x, Wf, Wi, Wu, Wo, bf, bi, bu, bo, zx);

    rec_kernel<<<1, 256, 0, stream>>>(
        Wf, Wi, Wu, Wo, phf, phi, phu, pho, zx, hv_tab, c_fin);

    bc_kernel<<<4 * T_DIM + 8, 256, 0, stream>>>(hv_tab, c_fin, (float*)d_out);
}